// Round 1
// baseline (1659.250 us; speedup 1.0000x reference)
//
#include <hip/hip_runtime.h>

typedef unsigned short u16;
typedef unsigned int u32;
typedef __attribute__((ext_vector_type(8))) short short8_t;
typedef __attribute__((ext_vector_type(4))) float f32x4;

#define HID 2048
#define KVH 512
#define NROW 4096   // B*S

__device__ __forceinline__ float bflo(u32 u){ return __builtin_bit_cast(float, u << 16); }
__device__ __forceinline__ float bfhi(u32 u){ return __builtin_bit_cast(float, u & 0xffff0000u); }
__device__ __forceinline__ u16 f2bf(float f){
  u32 u = __builtin_bit_cast(u32, f);
  u += 0x7fffu + ((u >> 16) & 1u);   // round-to-nearest-even
  return (u16)(u >> 16);
}

union FragAB { short8_t v; uint2 q[2]; };

// C[M,N] = A[M,K] @ B[K,N].  A: fp32 or bf16 row-major (ABF). B: fp32 row-major,
// converted to bf16 during staging. C: fp32 or bf16 (CBF).
// Block tile 128x128, BK=64, 4 waves (2x2), wave tile 64x64 = 4x4 mfma 16x16x32.
template<int ABF, int CBF>
__global__ __launch_bounds__(256)
void gemm_kernel(const void* __restrict__ Ap, const float* __restrict__ Bg,
                 void* __restrict__ Cp, int M, int N, int K)
{
  __shared__ __align__(16) u16 As[128 * 72];   // As[row][k], row stride 72
  __shared__ __align__(16) u16 Bs[128 * 72];   // Bs[n][k]  (transposed), row stride 72
  const int t = threadIdx.x;
  const int lane = t & 63, wid = t >> 6;
  const int wm = wid >> 1, wn = wid & 1;
  const int r = lane & 15, g = lane >> 4;
  const int m0 = blockIdx.y * 128, n0 = blockIdx.x * 128;

  f32x4 zero4 = {0.f, 0.f, 0.f, 0.f};
  f32x4 acc[4][4];
  #pragma unroll
  for (int i = 0; i < 4; i++)
    #pragma unroll
    for (int j = 0; j < 4; j++) acc[i][j] = zero4;

  for (int k0 = 0; k0 < K; k0 += 64) {
    __syncthreads();
    // ---- stage A tile (128 x 64) ----
    if (ABF) {
      const u16* Ag = (const u16*)Ap;
      #pragma unroll
      for (int p = 0; p < 4; p++) {
        int row = (t >> 3) + p * 32, c8 = (t & 7) * 8;
        uint4 v = *(const uint4*)(Ag + (size_t)(m0 + row) * K + k0 + c8);
        *(uint4*)(&As[row * 72 + c8]) = v;
      }
    } else {
      const float* Ag = (const float*)Ap;
      #pragma unroll
      for (int p = 0; p < 8; p++) {
        int row = (t >> 4) + p * 16, c4 = (t & 15) * 4;
        float4 v = *(const float4*)(Ag + (size_t)(m0 + row) * K + k0 + c4);
        ushort4 hv; hv.x = f2bf(v.x); hv.y = f2bf(v.y); hv.z = f2bf(v.z); hv.w = f2bf(v.w);
        *(ushort4*)(&As[row * 72 + c4]) = hv;
      }
    }
    // ---- stage B tile (64 x 128) transposed into Bs[n][k] ----
    {
      const int n = t & 127, kg = t >> 7;
      #pragma unroll
      for (int p = 0; p < 8; p++) {
        int kk = (p * 2 + kg) * 4;
        size_t base = (size_t)(k0 + kk) * N + n0 + n;
        float b0 = Bg[base];
        float b1 = Bg[base + (size_t)N];
        float b2 = Bg[base + (size_t)2 * N];
        float b3 = Bg[base + (size_t)3 * N];
        ushort4 hv; hv.x = f2bf(b0); hv.y = f2bf(b1); hv.z = f2bf(b2); hv.w = f2bf(b3);
        *(ushort4*)(&Bs[n * 72 + kk]) = hv;
      }
    }
    __syncthreads();
    // ---- MFMA over BK=64 (two K=32 steps) ----
    #pragma unroll
    for (int kk = 0; kk < 64; kk += 32) {
      FragAB a[4], b[4];
      #pragma unroll
      for (int mi = 0; mi < 4; mi++) {
        int row = wm * 64 + mi * 16 + r;
        a[mi].q[0] = *(const uint2*)(&As[row * 72 + kk + g * 4]);
        a[mi].q[1] = *(const uint2*)(&As[row * 72 + kk + 16 + g * 4]);
      }
      #pragma unroll
      for (int ni = 0; ni < 4; ni++) {
        int col = wn * 64 + ni * 16 + r;
        b[ni].q[0] = *(const uint2*)(&Bs[col * 72 + kk + g * 4]);
        b[ni].q[1] = *(const uint2*)(&Bs[col * 72 + kk + 16 + g * 4]);
      }
      #pragma unroll
      for (int mi = 0; mi < 4; mi++)
        #pragma unroll
        for (int ni = 0; ni < 4; ni++)
          acc[mi][ni] = __builtin_amdgcn_mfma_f32_16x16x32_bf16(a[mi].v, b[ni].v, acc[mi][ni], 0, 0, 0);
    }
  }
  // ---- epilogue: C row = 4*(lane>>4)+reg, col = lane&15 (HW-verified layout) ----
  #pragma unroll
  for (int mi = 0; mi < 4; mi++) {
    int row = m0 + wm * 64 + mi * 16 + g * 4;
    #pragma unroll
    for (int ni = 0; ni < 4; ni++) {
      int col = n0 + wn * 64 + ni * 16 + r;
      #pragma unroll
      for (int rr = 0; rr < 4; rr++) {
        if (CBF) ((u16*)Cp)[(size_t)(row + rr) * N + col] = f2bf(acc[mi][ni][rr]);
        else     ((float*)Cp)[(size_t)(row + rr) * N + col] = acc[mi][ni][rr];
      }
    }
  }
}

// Flash attention, fp32 VALU, causal, GQA (4 q-heads per kv head).
// Block = 256 threads, handles one (b, h, 64-row q block). K/V tiles of 64.
// Thread (tq,tk) owns q rows tq*4..+3, scores for keys tk*4..+3, and output
// dims tk*4..+3. P round-trips through LDS in bf16.
__global__ __launch_bounds__(256)
void attn_kernel(const u16* __restrict__ Q, const u16* __restrict__ K,
                 const u16* __restrict__ V, u16* __restrict__ O)
{
  __shared__ __align__(16) float Qs[64][68];
  __shared__ __align__(16) float Ks[64][68];
  __shared__ __align__(16) float Vs[64][68];
  __shared__ __align__(16) u16 Ps[64 * 72];
  const int qb = blockIdx.x, h = blockIdx.y, b = blockIdx.z;
  const int kvh = h >> 2;
  const int t = threadIdx.x;

  // stage Q (pre-scaled by 1/sqrt(64) = 0.125)
  {
    const u16* Qg = Q + (size_t)(b * 2048 + qb * 64) * 2048 + h * 64;
    #pragma unroll
    for (int p = 0; p < 2; p++) {
      int row = (t >> 3) + p * 32, d8 = (t & 7) * 8;
      uint4 v = *(const uint4*)(Qg + (size_t)row * 2048 + d8);
      u32 w[4] = {v.x, v.y, v.z, v.w};
      #pragma unroll
      for (int i = 0; i < 4; i++) {
        Qs[row][d8 + 2 * i]     = bflo(w[i]) * 0.125f;
        Qs[row][d8 + 2 * i + 1] = bfhi(w[i]) * 0.125f;
      }
    }
  }

  const int tq = t >> 4, tk = t & 15;
  float m_run[4], l_run[4], o[4][4];
  #pragma unroll
  for (int i = 0; i < 4; i++) {
    m_run[i] = -1e30f; l_run[i] = 0.f;
    #pragma unroll
    for (int d = 0; d < 4; d++) o[i][d] = 0.f;
  }

  const int ntiles = qb + 1;
  for (int jt = 0; jt < ntiles; ++jt) {
    __syncthreads();
    // stage K/V tile (64 keys x 64 dims)
    {
      const u16* Kg = K + (size_t)(b * 2048 + jt * 64) * 512 + kvh * 64;
      const u16* Vg = V + (size_t)(b * 2048 + jt * 64) * 512 + kvh * 64;
      #pragma unroll
      for (int p = 0; p < 2; p++) {
        int row = (t >> 3) + p * 32, d8 = (t & 7) * 8;
        uint4 kv4 = *(const uint4*)(Kg + (size_t)row * 512 + d8);
        u32 w[4] = {kv4.x, kv4.y, kv4.z, kv4.w};
        #pragma unroll
        for (int i = 0; i < 4; i++) {
          Ks[row][d8 + 2 * i]     = bflo(w[i]);
          Ks[row][d8 + 2 * i + 1] = bfhi(w[i]);
        }
        uint4 vv4 = *(const uint4*)(Vg + (size_t)row * 512 + d8);
        u32 x[4] = {vv4.x, vv4.y, vv4.z, vv4.w};
        #pragma unroll
        for (int i = 0; i < 4; i++) {
          Vs[row][d8 + 2 * i]     = bflo(x[i]);
          Vs[row][d8 + 2 * i + 1] = bfhi(x[i]);
        }
      }
    }
    __syncthreads();

    // scores: 4x4 per thread
    float s[4][4];
    #pragma unroll
    for (int i = 0; i < 4; i++)
      #pragma unroll
      for (int j = 0; j < 4; j++) s[i][j] = 0.f;
    for (int d4 = 0; d4 < 16; ++d4) {
      float4 qv[4], kv[4];
      #pragma unroll
      for (int i = 0; i < 4; i++) qv[i] = *(const float4*)&Qs[tq * 4 + i][d4 * 4];
      #pragma unroll
      for (int j = 0; j < 4; j++) kv[j] = *(const float4*)&Ks[tk * 4 + j][d4 * 4];
      #pragma unroll
      for (int i = 0; i < 4; i++)
        #pragma unroll
        for (int j = 0; j < 4; j++)
          s[i][j] += qv[i].x * kv[j].x + qv[i].y * kv[j].y + qv[i].z * kv[j].z + qv[i].w * kv[j].w;
    }
    if (jt == qb) {  // causal mask on diagonal tile
      #pragma unroll
      for (int i = 0; i < 4; i++)
        #pragma unroll
        for (int j = 0; j < 4; j++)
          if (tk * 4 + j > tq * 4 + i) s[i][j] = -1e30f;
    }

    // online softmax (row groups of 16 lanes share a q row)
    #pragma unroll
    for (int i = 0; i < 4; i++) {
      float rmax = fmaxf(fmaxf(s[i][0], s[i][1]), fmaxf(s[i][2], s[i][3]));
      #pragma unroll
      for (int msk = 1; msk < 16; msk <<= 1) rmax = fmaxf(rmax, __shfl_xor(rmax, msk));
      float m_new = fmaxf(m_run[i], rmax);
      float corr = __expf(m_run[i] - m_new);
      m_run[i] = m_new;
      float p0 = __expf(s[i][0] - m_new);
      float p1 = __expf(s[i][1] - m_new);
      float p2 = __expf(s[i][2] - m_new);
      float p3 = __expf(s[i][3] - m_new);
      float lsum = p0 + p1 + p2 + p3;
      #pragma unroll
      for (int msk = 1; msk < 16; msk <<= 1) lsum += __shfl_xor(lsum, msk);
      l_run[i] = l_run[i] * corr + lsum;
      #pragma unroll
      for (int d = 0; d < 4; d++) o[i][d] *= corr;
      ushort4 ps4; ps4.x = f2bf(p0); ps4.y = f2bf(p1); ps4.z = f2bf(p2); ps4.w = f2bf(p3);
      *(ushort4*)(&Ps[(tq * 4 + i) * 72 + tk * 4]) = ps4;
    }
    __syncthreads();

    // PV: o[i][d(own 4 dims)] += sum_j P[i][j] * V[j][d]
    for (int j4 = 0; j4 < 16; ++j4) {
      float p[4][4];
      #pragma unroll
      for (int i = 0; i < 4; i++) {
        uint2 pr = *(const uint2*)(&Ps[(tq * 4 + i) * 72 + j4 * 4]);
        p[i][0] = bflo(pr.x); p[i][1] = bfhi(pr.x);
        p[i][2] = bflo(pr.y); p[i][3] = bfhi(pr.y);
      }
      float vr[4][4];
      #pragma unroll
      for (int jj = 0; jj < 4; jj++) {
        float4 tmp = *(const float4*)&Vs[j4 * 4 + jj][tk * 4];
        vr[jj][0] = tmp.x; vr[jj][1] = tmp.y; vr[jj][2] = tmp.z; vr[jj][3] = tmp.w;
      }
      #pragma unroll
      for (int i = 0; i < 4; i++)
        #pragma unroll
        for (int d = 0; d < 4; d++)
          o[i][d] += p[i][0] * vr[0][d] + p[i][1] * vr[1][d] + p[i][2] * vr[2][d] + p[i][3] * vr[3][d];
    }
  }

  // write attention output (bf16) to AO[b*2048+s][h*64+d]
  u16* Og = O + (size_t)(b * 2048 + qb * 64) * 2048 + h * 64;
  #pragma unroll
  for (int i = 0; i < 4; i++) {
    float inv = 1.f / l_run[i];
    ushort4 hv;
    hv.x = f2bf(o[i][0] * inv); hv.y = f2bf(o[i][1] * inv);
    hv.z = f2bf(o[i][2] * inv); hv.w = f2bf(o[i][3] * inv);
    *(ushort4*)(Og + (size_t)(tq * 4 + i) * 2048 + tk * 4) = hv;
  }
}

extern "C" void kernel_launch(void* const* d_in, const int* in_sizes, int n_in,
                              void* d_out, int out_size, void* d_ws, size_t ws_size,
                              hipStream_t stream)
{
  (void)in_sizes; (void)n_in; (void)out_size; (void)ws_size;
  const float* X  = (const float*)d_in[0];
  const float* Wq = (const float*)d_in[1];
  const float* Wk = (const float*)d_in[2];
  const float* Wv = (const float*)d_in[3];
  const float* Wo = (const float*)d_in[4];
  float* out = (float*)d_out;

  // workspace: Q(bf16 16MB) | K(4MB) | V(4MB) | AO(16MB)  = 40MB
  u16* Qb  = (u16*)d_ws;
  u16* Kb  = Qb + (size_t)NROW * HID;
  u16* Vb  = Kb + (size_t)NROW * KVH;
  u16* AOb = Vb + (size_t)NROW * KVH;

  gemm_kernel<0, 1><<<dim3(HID / 128, NROW / 128), 256, 0, stream>>>(X, Wq, Qb, NROW, HID, HID);
  gemm_kernel<0, 1><<<dim3(KVH / 128, NROW / 128), 256, 0, stream>>>(X, Wk, Kb, NROW, KVH, HID);
  gemm_kernel<0, 1><<<dim3(KVH / 128, NROW / 128), 256, 0, stream>>>(X, Wv, Vb, NROW, KVH, HID);
  attn_kernel<<<dim3(32, 32, 2), 256, 0, stream>>>(Qb, Kb, Vb, AOb);
  gemm_kernel<1, 0><<<dim3(HID / 128, NROW / 128), 256, 0, stream>>>(AOb, Wo, out, NROW, HID, HID);
}

// Round 2
// 687.989 us; speedup vs baseline: 2.4117x; 2.4117x over previous
//
#include <hip/hip_runtime.h>

typedef unsigned short u16;
typedef unsigned int u32;
typedef __attribute__((ext_vector_type(8))) short short8_t;
typedef __attribute__((ext_vector_type(4))) float f32x4;

#define HID 2048
#define KVH 512
#define NROW 4096   // B*S
#define SC2 0.18033688011112042f   // (1/sqrt(64)) * log2(e)

__device__ __forceinline__ float bflo(u32 u){ return __builtin_bit_cast(float, u << 16); }
__device__ __forceinline__ float bfhi(u32 u){ return __builtin_bit_cast(float, u & 0xffff0000u); }
__device__ __forceinline__ u16 f2bf(float f){
  u32 u = __builtin_bit_cast(u32, f);
  u += 0x7fffu + ((u >> 16) & 1u);   // round-to-nearest-even
  return (u16)(u >> 16);
}

union FragAB { short8_t v; uint2 q[2]; };

// C[M,N] = A[M,K] @ B[K,N].  A: fp32 or bf16 row-major (ABF). B: fp32 row-major,
// converted to bf16 during staging. C: fp32 or bf16 (CBF).
// Block tile 128x128, BK=64, 4 waves (2x2), wave tile 64x64 = 4x4 mfma 16x16x32.
template<int ABF, int CBF>
__global__ __launch_bounds__(256)
void gemm_kernel(const void* __restrict__ Ap, const float* __restrict__ Bg,
                 void* __restrict__ Cp, int M, int N, int K)
{
  __shared__ __align__(16) u16 As[128 * 72];   // As[row][k], row stride 72
  __shared__ __align__(16) u16 Bs[128 * 72];   // Bs[n][k]  (transposed), row stride 72
  const int t = threadIdx.x;
  const int lane = t & 63, wid = t >> 6;
  const int wm = wid >> 1, wn = wid & 1;
  const int r = lane & 15, g = lane >> 4;
  const int m0 = blockIdx.y * 128, n0 = blockIdx.x * 128;

  f32x4 zero4 = {0.f, 0.f, 0.f, 0.f};
  f32x4 acc[4][4];
  #pragma unroll
  for (int i = 0; i < 4; i++)
    #pragma unroll
    for (int j = 0; j < 4; j++) acc[i][j] = zero4;

  for (int k0 = 0; k0 < K; k0 += 64) {
    __syncthreads();
    // ---- stage A tile (128 x 64) ----
    if (ABF) {
      const u16* Ag = (const u16*)Ap;
      #pragma unroll
      for (int p = 0; p < 4; p++) {
        int row = (t >> 3) + p * 32, c8 = (t & 7) * 8;
        uint4 v = *(const uint4*)(Ag + (size_t)(m0 + row) * K + k0 + c8);
        *(uint4*)(&As[row * 72 + c8]) = v;
      }
    } else {
      const float* Ag = (const float*)Ap;
      #pragma unroll
      for (int p = 0; p < 8; p++) {
        int row = (t >> 4) + p * 16, c4 = (t & 15) * 4;
        float4 v = *(const float4*)(Ag + (size_t)(m0 + row) * K + k0 + c4);
        ushort4 hv; hv.x = f2bf(v.x); hv.y = f2bf(v.y); hv.z = f2bf(v.z); hv.w = f2bf(v.w);
        *(ushort4*)(&As[row * 72 + c4]) = hv;
      }
    }
    // ---- stage B tile (64 x 128) transposed into Bs[n][k] ----
    {
      const int n = t & 127, kg = t >> 7;
      #pragma unroll
      for (int p = 0; p < 8; p++) {
        int kk = (p * 2 + kg) * 4;
        size_t base = (size_t)(k0 + kk) * N + n0 + n;
        float b0 = Bg[base];
        float b1 = Bg[base + (size_t)N];
        float b2 = Bg[base + (size_t)2 * N];
        float b3 = Bg[base + (size_t)3 * N];
        ushort4 hv; hv.x = f2bf(b0); hv.y = f2bf(b1); hv.z = f2bf(b2); hv.w = f2bf(b3);
        *(ushort4*)(&Bs[n * 72 + kk]) = hv;
      }
    }
    __syncthreads();
    // ---- MFMA over BK=64 (two K=32 steps) ----
    #pragma unroll
    for (int kk = 0; kk < 64; kk += 32) {
      FragAB a[4], b[4];
      #pragma unroll
      for (int mi = 0; mi < 4; mi++) {
        int row = wm * 64 + mi * 16 + r;
        a[mi].q[0] = *(const uint2*)(&As[row * 72 + kk + g * 4]);
        a[mi].q[1] = *(const uint2*)(&As[row * 72 + kk + 16 + g * 4]);
      }
      #pragma unroll
      for (int ni = 0; ni < 4; ni++) {
        int col = wn * 64 + ni * 16 + r;
        b[ni].q[0] = *(const uint2*)(&Bs[col * 72 + kk + g * 4]);
        b[ni].q[1] = *(const uint2*)(&Bs[col * 72 + kk + 16 + g * 4]);
      }
      #pragma unroll
      for (int mi = 0; mi < 4; mi++)
        #pragma unroll
        for (int ni = 0; ni < 4; ni++)
          acc[mi][ni] = __builtin_amdgcn_mfma_f32_16x16x32_bf16(a[mi].v, b[ni].v, acc[mi][ni], 0, 0, 0);
    }
  }
  // ---- epilogue: C row = 4*(lane>>4)+reg, col = lane&15 (HW-verified layout) ----
  #pragma unroll
  for (int mi = 0; mi < 4; mi++) {
    int row = m0 + wm * 64 + mi * 16 + g * 4;
    #pragma unroll
    for (int ni = 0; ni < 4; ni++) {
      int col = n0 + wn * 64 + ni * 16 + r;
      #pragma unroll
      for (int rr = 0; rr < 4; rr++) {
        if (CBF) ((u16*)Cp)[(size_t)(row + rr) * N + col] = f2bf(acc[mi][ni][rr]);
        else     ((float*)Cp)[(size_t)(row + rr) * N + col] = acc[mi][ni][rr];
      }
    }
  }
}

// MFMA flash attention. Block = 256 threads = 4 waves, QBLK=128 (32 q-rows/wave,
// Q in registers), KV tile 64, causal, GQA 4:1. Softmax in log2 domain.
// P round-trips LDS in bf16 (each wave owns its rows -> no extra barrier).
// V staged transposed (in-register 4x4 transpose) so PV B-frags read key-contiguous.
__global__ __launch_bounds__(256)
void attn_mfma(const u16* __restrict__ Q, const u16* __restrict__ K,
               const u16* __restrict__ V, u16* __restrict__ O)
{
  __shared__ __align__(16) u16 Ks[64 * 72];    // [key][dim]
  __shared__ __align__(16) u16 Vt[64 * 72];    // [dim][key]
  __shared__ __align__(16) u16 Ps[128 * 68];   // [qrow_local][key]
  const int qb = blockIdx.x, h = blockIdx.y, b = blockIdx.z;
  const int kvh = h >> 2;
  const int t = threadIdx.x, lane = t & 63, w = t >> 6;
  const int r = lane & 15, g = lane >> 4;

  // ---- Q fragments in registers (rows qb*128 + w*32 + mb*16 + r) ----
  FragAB qf[2][2];
  {
    const u16* Qg = Q + ((size_t)(b * 2048 + qb * 128 + w * 32)) * 2048 + h * 64;
    #pragma unroll
    for (int mb = 0; mb < 2; mb++)
      #pragma unroll
      for (int ks = 0; ks < 2; ks++) {
        const u16* base = Qg + (size_t)(mb * 16 + r) * 2048 + ks * 32 + g * 4;
        qf[mb][ks].q[0] = *(const uint2*)(base);
        qf[mb][ks].q[1] = *(const uint2*)(base + 16);
      }
  }

  float m_run[2][4], l_run[2][4];
  f32x4 o[2][4];
  #pragma unroll
  for (int mb = 0; mb < 2; mb++)
    #pragma unroll
    for (int i = 0; i < 4; i++) {
      m_run[mb][i] = -1e30f; l_run[mb][i] = 0.f;
      o[mb][i] = (f32x4){0.f, 0.f, 0.f, 0.f};
    }

  const u16* Kg0 = K + (size_t)(b * 2048) * 512 + kvh * 64;
  const u16* Vg0 = V + (size_t)(b * 2048) * 512 + kvh * 64;
  const int ntiles = 2 * qb + 2;

  for (int jt = 0; jt < ntiles; ++jt) {
    __syncthreads();
    // ---- stage K tile [64 keys x 64 dims] ----
    {
      const u16* Kg = Kg0 + (size_t)(jt * 64) * 512;
      int row = t >> 3, d8 = (t & 7) * 8;
      *(uint4*)&Ks[row * 72 + d8] = *(const uint4*)(Kg + (size_t)row * 512 + d8);
      *(uint4*)&Ks[(row + 32) * 72 + d8] = *(const uint4*)(Kg + (size_t)(row + 32) * 512 + d8);
    }
    // ---- stage V transposed: Vt[dim][key] ----
    {
      const u16* Vg = Vg0 + (size_t)(jt * 64) * 512;
      int d4 = (t & 15) * 4, k4 = (t >> 4) * 4;
      ushort4 vv[4];
      #pragma unroll
      for (int j = 0; j < 4; j++)
        vv[j] = *(const ushort4*)(Vg + (size_t)(k4 + j) * 512 + d4);
      const u16* vp = (const u16*)vv;
      #pragma unroll
      for (int i = 0; i < 4; i++) {
        ushort4 tv;
        tv.x = vp[0 * 4 + i]; tv.y = vp[1 * 4 + i];
        tv.z = vp[2 * 4 + i]; tv.w = vp[3 * 4 + i];
        *(ushort4*)&Vt[(d4 + i) * 72 + k4] = tv;
      }
    }
    __syncthreads();

    // waves whose rows are all below this KV tile skip compute (wave-uniform)
    if (jt * 64 <= qb * 128 + w * 32 + 31) {
      // ---- QK^T: S[32 x 64] per wave ----
      f32x4 s[2][4];
      #pragma unroll
      for (int mb = 0; mb < 2; mb++)
        #pragma unroll
        for (int nb = 0; nb < 4; nb++) s[mb][nb] = (f32x4){0.f, 0.f, 0.f, 0.f};
      #pragma unroll
      for (int ks = 0; ks < 2; ks++) {
        FragAB bf[4];
        #pragma unroll
        for (int nb = 0; nb < 4; nb++) {
          const u16* base = &Ks[(nb * 16 + r) * 72 + ks * 32 + g * 4];
          bf[nb].q[0] = *(const uint2*)(base);
          bf[nb].q[1] = *(const uint2*)(base + 16);
        }
        #pragma unroll
        for (int mb = 0; mb < 2; mb++)
          #pragma unroll
          for (int nb = 0; nb < 4; nb++)
            s[mb][nb] = __builtin_amdgcn_mfma_f32_16x16x32_bf16(qf[mb][ks].v, bf[nb].v, s[mb][nb], 0, 0, 0);
      }

      // ---- online softmax (log2 domain), rows = w*32 + mb*16 + g*4 + rr ----
      #pragma unroll
      for (int mb = 0; mb < 2; mb++) {
        float sl[4][4];   // [nb][rr]
        #pragma unroll
        for (int nb = 0; nb < 4; nb++)
          #pragma unroll
          for (int rr = 0; rr < 4; rr++) sl[nb][rr] = s[mb][nb][rr] * SC2;
        if (jt >= 2 * qb) {   // (partially) masked tile
          int rowg = qb * 128 + w * 32 + mb * 16 + g * 4;
          int colb = jt * 64 + r;
          #pragma unroll
          for (int nb = 0; nb < 4; nb++)
            #pragma unroll
            for (int rr = 0; rr < 4; rr++)
              if (colb + nb * 16 > rowg + rr) sl[nb][rr] = -1e30f;
        }
        float pm[4], corr[4];
        #pragma unroll
        for (int rr = 0; rr < 4; rr++)
          pm[rr] = fmaxf(fmaxf(sl[0][rr], sl[1][rr]), fmaxf(sl[2][rr], sl[3][rr]));
        #pragma unroll
        for (int rr = 0; rr < 4; rr++)
          #pragma unroll
          for (int msk = 1; msk < 16; msk <<= 1)
            pm[rr] = fmaxf(pm[rr], __shfl_xor(pm[rr], msk));
        #pragma unroll
        for (int rr = 0; rr < 4; rr++) {
          float mn = fmaxf(m_run[mb][rr], pm[rr]);
          corr[rr] = exp2f(m_run[mb][rr] - mn);
          m_run[mb][rr] = mn;
        }
        float ls[4] = {0.f, 0.f, 0.f, 0.f};
        #pragma unroll
        for (int nb = 0; nb < 4; nb++) {
          #pragma unroll
          for (int rr = 0; rr < 4; rr++) {
            float p = exp2f(sl[nb][rr] - m_run[mb][rr]);
            ls[rr] += p;
            Ps[(w * 32 + mb * 16 + g * 4 + rr) * 68 + nb * 16 + r] = f2bf(p);
          }
        }
        #pragma unroll
        for (int rr = 0; rr < 4; rr++)
          #pragma unroll
          for (int msk = 1; msk < 16; msk <<= 1)
            ls[rr] += __shfl_xor(ls[rr], msk);
        #pragma unroll
        for (int rr = 0; rr < 4; rr++)
          l_run[mb][rr] = l_run[mb][rr] * corr[rr] + ls[rr];
        #pragma unroll
        for (int nd = 0; nd < 4; nd++)
          #pragma unroll
          for (int rr = 0; rr < 4; rr++)
            o[mb][nd][rr] *= corr[rr];
      }

      // ---- PV: O[32 x 64] += P[32 x 64] @ V[64 x 64] ----
      #pragma unroll
      for (int ks = 0; ks < 2; ks++) {
        FragAB vf[4], pa[2];
        #pragma unroll
        for (int nd = 0; nd < 4; nd++) {
          const u16* base = &Vt[(nd * 16 + r) * 72 + ks * 32 + g * 4];
          vf[nd].q[0] = *(const uint2*)(base);
          vf[nd].q[1] = *(const uint2*)(base + 16);
        }
        #pragma unroll
        for (int mb = 0; mb < 2; mb++) {
          const u16* base = &Ps[(w * 32 + mb * 16 + r) * 68 + ks * 32 + g * 4];
          pa[mb].q[0] = *(const uint2*)(base);
          pa[mb].q[1] = *(const uint2*)(base + 16);
        }
        #pragma unroll
        for (int mb = 0; mb < 2; mb++)
          #pragma unroll
          for (int nd = 0; nd < 4; nd++)
            o[mb][nd] = __builtin_amdgcn_mfma_f32_16x16x32_bf16(pa[mb].v, vf[nd].v, o[mb][nd], 0, 0, 0);
      }
    }
  }

  // ---- epilogue ----
  u16* Og = O + ((size_t)(b * 2048 + qb * 128 + w * 32)) * 2048 + h * 64;
  #pragma unroll
  for (int mb = 0; mb < 2; mb++)
    #pragma unroll
    for (int rr = 0; rr < 4; rr++) {
      float inv = 1.f / l_run[mb][rr];
      #pragma unroll
      for (int nd = 0; nd < 4; nd++)
        Og[(size_t)(mb * 16 + g * 4 + rr) * 2048 + nd * 16 + r] = f2bf(o[mb][nd][rr] * inv);
    }
}

extern "C" void kernel_launch(void* const* d_in, const int* in_sizes, int n_in,
                              void* d_out, int out_size, void* d_ws, size_t ws_size,
                              hipStream_t stream)
{
  (void)in_sizes; (void)n_in; (void)out_size; (void)ws_size;
  const float* X  = (const float*)d_in[0];
  const float* Wq = (const float*)d_in[1];
  const float* Wk = (const float*)d_in[2];
  const float* Wv = (const float*)d_in[3];
  const float* Wo = (const float*)d_in[4];
  float* out = (float*)d_out;

  // workspace: Q(bf16 16MB) | K(4MB) | V(4MB) | AO(16MB)  = 40MB
  u16* Qb  = (u16*)d_ws;
  u16* Kb  = Qb + (size_t)NROW * HID;
  u16* Vb  = Kb + (size_t)NROW * KVH;
  u16* AOb = Vb + (size_t)NROW * KVH;

  gemm_kernel<0, 1><<<dim3(HID / 128, NROW / 128), 256, 0, stream>>>(X, Wq, Qb, NROW, HID, HID);
  gemm_kernel<0, 1><<<dim3(KVH / 128, NROW / 128), 256, 0, stream>>>(X, Wk, Kb, NROW, KVH, HID);
  gemm_kernel<0, 1><<<dim3(KVH / 128, NROW / 128), 256, 0, stream>>>(X, Wv, Vb, NROW, KVH, HID);
  attn_mfma<<<dim3(16, 32, 2), 256, 0, stream>>>(Qb, Kb, Vb, AOb);
  gemm_kernel<1, 0><<<dim3(HID / 128, NROW / 128), 256, 0, stream>>>(AOb, Wo, out, NROW, HID, HID);
}

// Round 3
// 280.703 us; speedup vs baseline: 5.9110x; 2.4509x over previous
//
#include <hip/hip_runtime.h>

typedef unsigned short u16;
typedef unsigned int u32;
typedef __attribute__((ext_vector_type(8))) short short8_t;
typedef __attribute__((ext_vector_type(4))) float f32x4;

#define HID 2048
#define KVH 512
#define NROW 4096   // B*S
#define SC2 0.18033688011112042f   // (1/sqrt(64)) * log2(e)

__device__ __forceinline__ u16 f2bf(float f){
  u32 u = __builtin_bit_cast(u32, f);
  u += 0x7fffu + ((u >> 16) & 1u);   // round-to-nearest-even
  return (u16)(u >> 16);
}
__device__ __forceinline__ u32 pack2(float a, float b){
  return (u32)f2bf(a) | ((u32)f2bf(b) << 16);
}

union FragAB { short8_t v; uint4 u4; uint2 q[2]; };

__device__ __forceinline__ void gload_lds16(const u16* g, u16* l){
  __builtin_amdgcn_global_load_lds((const __attribute__((address_space(1))) void*)g,
                                   (__attribute__((address_space(3))) void*)l, 16, 0, 0);
}

// ---------- prep: fp32 -> bf16 convert ----------
__global__ __launch_bounds__(256)
void conv_bf16(const float* __restrict__ X, u16* __restrict__ Y, int n4)
{
  for (int i = blockIdx.x * 256 + threadIdx.x; i < n4; i += gridDim.x * 256) {
    float4 v = ((const float4*)X)[i];
    ushort4 h; h.x = f2bf(v.x); h.y = f2bf(v.y); h.z = f2bf(v.z); h.w = f2bf(v.w);
    ((ushort4*)Y)[i] = h;
  }
}

// ---------- prep: W[K][N] fp32 -> Wt[N][K] bf16 ----------
__global__ __launch_bounds__(256)
void transpose_conv(const float* __restrict__ W, u16* __restrict__ Wt, int K, int N)
{
  __shared__ float tile[32][33];
  int x = blockIdx.x * 32 + threadIdx.x;
  int y0 = blockIdx.y * 32;
  #pragma unroll
  for (int j = threadIdx.y; j < 32; j += 8)
    tile[j][threadIdx.x] = W[(size_t)(y0 + j) * N + x];
  __syncthreads();
  #pragma unroll
  for (int j = threadIdx.y; j < 32; j += 8)
    Wt[(size_t)(blockIdx.x * 32 + j) * K + y0 + threadIdx.x] = f2bf(tile[threadIdx.x][j]);
}

// ---------- bf16 GEMM, B^T input (m97 structure) ----------
// C[M,N] = A[M,K] @ Bt[N,K]^T.  128x128 tile, BK=64, global_load_lds staging,
// linear LDS, contiguous-sigma ds_read_b128 fragments, 4 waves 2x2.
// Block column bx < nsplit uses (B0,C0), else (B1,C1) -> fuses K+V projections.
template<int CBF>
__global__ __launch_bounds__(256)
void gemm_bt(const u16* __restrict__ A, const u16* __restrict__ B0,
             const u16* __restrict__ B1, void* __restrict__ C0,
             void* __restrict__ C1, int nsplit, int N, int K)
{
  __shared__ __align__(16) u16 As[128 * 64];
  __shared__ __align__(16) u16 Bs[128 * 64];
  const int t = threadIdx.x, lane = t & 63, wid = t >> 6;
  const int wm = wid >> 1, wn = wid & 1;
  const int r = lane & 15, g = lane >> 4;
  const u16* Bt; char* Cp; int n0;
  if ((int)blockIdx.x < nsplit) { Bt = B0; Cp = (char*)C0; n0 = blockIdx.x * 128; }
  else { Bt = B1; Cp = (char*)C1; n0 = ((int)blockIdx.x - nsplit) * 128; }
  const int m0 = blockIdx.y * 128;

  f32x4 acc[4][4];
  #pragma unroll
  for (int i = 0; i < 4; i++)
    #pragma unroll
    for (int j = 0; j < 4; j++) acc[i][j] = (f32x4){0.f, 0.f, 0.f, 0.f};

  const u16* Arow = A + (size_t)m0 * K;
  const u16* Brow = Bt + (size_t)n0 * K;
  const int lrow = t >> 3, lcol = (t & 7) * 8;   // 16B slice: row c*32+lrow, col lcol

  for (int k0 = 0; k0 < K; k0 += 64) {
    __syncthreads();
    #pragma unroll
    for (int c = 0; c < 4; ++c) {
      gload_lds16(Arow + (size_t)(c * 32 + lrow) * K + k0 + lcol, As + c * 2048 + wid * 512);
      gload_lds16(Brow + (size_t)(c * 32 + lrow) * K + k0 + lcol, Bs + c * 2048 + wid * 512);
    }
    __syncthreads();
    #pragma unroll
    for (int kk = 0; kk < 64; kk += 32) {
      FragAB a[4], b[4];
      #pragma unroll
      for (int mi = 0; mi < 4; mi++)
        a[mi].u4 = *(const uint4*)&As[(wm * 64 + mi * 16 + r) * 64 + kk + g * 8];
      #pragma unroll
      for (int ni = 0; ni < 4; ni++)
        b[ni].u4 = *(const uint4*)&Bs[(wn * 64 + ni * 16 + r) * 64 + kk + g * 8];
      #pragma unroll
      for (int mi = 0; mi < 4; mi++)
        #pragma unroll
        for (int ni = 0; ni < 4; ni++)
          acc[mi][ni] = __builtin_amdgcn_mfma_f32_16x16x32_bf16(a[mi].v, b[ni].v, acc[mi][ni], 0, 0, 0);
    }
  }
  #pragma unroll
  for (int mi = 0; mi < 4; mi++) {
    int row = m0 + wm * 64 + mi * 16 + g * 4;
    #pragma unroll
    for (int ni = 0; ni < 4; ni++) {
      int col = n0 + wn * 64 + ni * 16 + r;
      #pragma unroll
      for (int rr = 0; rr < 4; rr++) {
        if (CBF) ((u16*)Cp)[(size_t)(row + rr) * N + col] = f2bf(acc[mi][ni][rr]);
        else     ((float*)Cp)[(size_t)(row + rr) * N + col] = acc[mi][ni][rr];
      }
    }
  }
}

// ---------- MFMA flash attention, swapped-operand layout ----------
// 4 waves, QBLK=128 (32 q-rows/wave, Q in regs). Swapped QK^T: st = mfma(K,Q)
// puts a full q-row's scores in-lane (col=lane&15) -> in-lane softmax, 2 shuffles.
// P packed to bf16 B-frags in registers (no LDS round-trip). PV swapped:
// o^T = mfma(V^T, P^T). Causal, GQA 4:1, log2-domain online softmax.
__device__ __forceinline__ void attn_block(const u16* __restrict__ Q, const u16* __restrict__ K,
    const u16* __restrict__ V, u16* __restrict__ O, u16* Ks, u16* Vt,
    int qb, int h, int b)
{
  const int t = threadIdx.x, lane = t & 63, w = t >> 6;
  const int r = lane & 15, g = lane >> 4;
  const int kvh = h >> 2;

  FragAB qf[2][2];
  {
    const u16* Qg = Q + ((size_t)(b * 2048 + qb * 128 + w * 32)) * 2048 + h * 64;
    #pragma unroll
    for (int mb = 0; mb < 2; mb++)
      #pragma unroll
      for (int ks = 0; ks < 2; ks++)
        qf[mb][ks].u4 = *(const uint4*)(Qg + (size_t)(mb * 16 + r) * 2048 + ks * 32 + g * 8);
  }

  float m_run[2] = {-1e30f, -1e30f}, l_run[2] = {0.f, 0.f};
  f32x4 o[2][4];
  #pragma unroll
  for (int mb = 0; mb < 2; mb++)
    #pragma unroll
    for (int nd = 0; nd < 4; nd++) o[mb][nd] = (f32x4){0.f, 0.f, 0.f, 0.f};

  const u16* Kg0 = K + (size_t)(b * 2048) * 512 + kvh * 64;
  const u16* Vg0 = V + (size_t)(b * 2048) * 512 + kvh * 64;
  const int ntiles = 2 * qb + 2;

  for (int jt = 0; jt < ntiles; ++jt) {
    __syncthreads();
    {  // stage K [key][dim] and V^T [dim][key], both pad-72
      const u16* Kg = Kg0 + (size_t)(jt * 64) * 512;
      int row = t >> 3, d8 = (t & 7) * 8;
      *(uint4*)&Ks[row * 72 + d8] = *(const uint4*)(Kg + (size_t)row * 512 + d8);
      *(uint4*)&Ks[(row + 32) * 72 + d8] = *(const uint4*)(Kg + (size_t)(row + 32) * 512 + d8);
      const u16* Vg = Vg0 + (size_t)(jt * 64) * 512;
      int d4 = (t & 15) * 4, k4 = (t >> 4) * 4;
      ushort4 vv[4];
      #pragma unroll
      for (int j = 0; j < 4; j++)
        vv[j] = *(const ushort4*)(Vg + (size_t)(k4 + j) * 512 + d4);
      const u16* vp = (const u16*)vv;
      #pragma unroll
      for (int i = 0; i < 4; i++) {
        ushort4 tv; tv.x = vp[i]; tv.y = vp[4 + i]; tv.z = vp[8 + i]; tv.w = vp[12 + i];
        *(ushort4*)&Vt[(d4 + i) * 72 + k4] = tv;
      }
    }
    __syncthreads();

    if (jt * 64 <= qb * 128 + w * 32 + 31) {  // wave participates
      // QK^T swapped: st[mb][kb][i] = S[qrow = mb*16 + r][key = kb*16 + g*4 + i]
      f32x4 st[2][4];
      #pragma unroll
      for (int mb = 0; mb < 2; mb++)
        #pragma unroll
        for (int kb = 0; kb < 4; kb++) st[mb][kb] = (f32x4){0.f, 0.f, 0.f, 0.f};
      #pragma unroll
      for (int ks = 0; ks < 2; ks++) {
        FragAB kf[4];
        #pragma unroll
        for (int kb = 0; kb < 4; kb++)
          kf[kb].u4 = *(const uint4*)&Ks[(kb * 16 + r) * 72 + ks * 32 + g * 8];
        #pragma unroll
        for (int mb = 0; mb < 2; mb++)
          #pragma unroll
          for (int kb = 0; kb < 4; kb++)
            st[mb][kb] = __builtin_amdgcn_mfma_f32_16x16x32_bf16(kf[kb].v, qf[mb][ks].v, st[mb][kb], 0, 0, 0);
      }

      FragAB pa[2][2];
      #pragma unroll
      for (int mb = 0; mb < 2; mb++) {
        float sl[4][4];
        #pragma unroll
        for (int kb = 0; kb < 4; kb++)
          #pragma unroll
          for (int i = 0; i < 4; i++) sl[kb][i] = st[mb][kb][i] * SC2;
        const int rowg = qb * 128 + w * 32 + mb * 16 + r;
        if (jt * 64 + 63 > qb * 128 + w * 32 + mb * 16) {   // tile crosses diagonal
          #pragma unroll
          for (int kb = 0; kb < 4; kb++)
            #pragma unroll
            for (int i = 0; i < 4; i++)
              if (jt * 64 + kb * 16 + g * 4 + i > rowg) sl[kb][i] = -1e30f;
        }
        float pm = sl[0][0];
        #pragma unroll
        for (int kb = 0; kb < 4; kb++)
          #pragma unroll
          for (int i = 0; i < 4; i++) pm = fmaxf(pm, sl[kb][i]);
        pm = fmaxf(pm, __shfl_xor(pm, 16));
        pm = fmaxf(pm, __shfl_xor(pm, 32));
        float mn = fmaxf(m_run[mb], pm);
        float corr = exp2f(m_run[mb] - mn);
        m_run[mb] = mn;
        float p[4][4]; float ls = 0.f;
        #pragma unroll
        for (int kb = 0; kb < 4; kb++)
          #pragma unroll
          for (int i = 0; i < 4; i++) { p[kb][i] = exp2f(sl[kb][i] - mn); ls += p[kb][i]; }
        ls += __shfl_xor(ls, 16);
        ls += __shfl_xor(ls, 32);
        l_run[mb] = l_run[mb] * corr + ls;
        #pragma unroll
        for (int nd = 0; nd < 4; nd++)
          #pragma unroll
          for (int i = 0; i < 4; i++) o[mb][nd][i] *= corr;
        // pack P^T B-frags: pos j<4 -> key ks*32+g*4+j; pos j>=4 -> +16
        #pragma unroll
        for (int ks = 0; ks < 2; ks++) {
          pa[mb][ks].q[0] = make_uint2(pack2(p[2 * ks][0], p[2 * ks][1]),
                                       pack2(p[2 * ks][2], p[2 * ks][3]));
          pa[mb][ks].q[1] = make_uint2(pack2(p[2 * ks + 1][0], p[2 * ks + 1][1]),
                                       pack2(p[2 * ks + 1][2], p[2 * ks + 1][3]));
        }
      }

      // PV swapped: o^T += V^T @ P^T  (o[mb][nd][i] = O[qrow=mb*16+r][d=nd*16+g*4+i])
      #pragma unroll
      for (int ks = 0; ks < 2; ks++) {
        FragAB vf[4];
        #pragma unroll
        for (int nd = 0; nd < 4; nd++) {
          const u16* base = &Vt[(nd * 16 + r) * 72 + ks * 32 + g * 4];
          vf[nd].q[0] = *(const uint2*)(base);
          vf[nd].q[1] = *(const uint2*)(base + 16);
        }
        #pragma unroll
        for (int mb = 0; mb < 2; mb++)
          #pragma unroll
          for (int nd = 0; nd < 4; nd++)
            o[mb][nd] = __builtin_amdgcn_mfma_f32_16x16x32_bf16(vf[nd].v, pa[mb][ks].v, o[mb][nd], 0, 0, 0);
      }
    }
  }

  u16* Og = O + ((size_t)(b * 2048 + qb * 128 + w * 32)) * 2048 + h * 64;
  #pragma unroll
  for (int mb = 0; mb < 2; mb++) {
    float inv = 1.f / l_run[mb];
    #pragma unroll
    for (int nd = 0; nd < 4; nd++) {
      ushort4 hv;
      hv.x = f2bf(o[mb][nd][0] * inv); hv.y = f2bf(o[mb][nd][1] * inv);
      hv.z = f2bf(o[mb][nd][2] * inv); hv.w = f2bf(o[mb][nd][3] * inv);
      *(ushort4*)(Og + (size_t)(mb * 16 + r) * 2048 + nd * 16 + g * 4) = hv;
    }
  }
}

// Paired q-blocks (bx, 15-bx): constant work per block -> balanced CUs.
__global__ __launch_bounds__(256)
void attn_mfma(const u16* __restrict__ Q, const u16* __restrict__ K,
               const u16* __restrict__ V, u16* __restrict__ O)
{
  __shared__ __align__(16) u16 Ks[64 * 72];
  __shared__ __align__(16) u16 Vt[64 * 72];
  const int h = blockIdx.y, b = blockIdx.z;
  attn_block(Q, K, V, O, Ks, Vt, (int)blockIdx.x, h, b);
  attn_block(Q, K, V, O, Ks, Vt, 15 - (int)blockIdx.x, h, b);
}

extern "C" void kernel_launch(void* const* d_in, const int* in_sizes, int n_in,
                              void* d_out, int out_size, void* d_ws, size_t ws_size,
                              hipStream_t stream)
{
  (void)in_sizes; (void)n_in; (void)out_size; (void)ws_size;
  const float* X  = (const float*)d_in[0];
  const float* Wq = (const float*)d_in[1];
  const float* Wk = (const float*)d_in[2];
  const float* Wv = (const float*)d_in[3];
  const float* Wo = (const float*)d_in[4];
  float* out = (float*)d_out;

  // ws layout (u16), 54.6 MB total with aliasing
  u16* Xb  = (u16*)d_ws;                         // [4096][2048]
  u16* Qb  = Xb  + (size_t)NROW * HID;
  u16* Kb  = Qb  + (size_t)NROW * HID;
  u16* Vb  = Kb  + (size_t)NROW * KVH;
  u16* Wqt = Vb  + (size_t)NROW * KVH;           // [2048][2048]
  u16* Wkt = Wqt + (size_t)HID * HID;            // [512][2048]
  u16* Wvt = Wkt + (size_t)HID * KVH;
  u16* AOb = Xb;    // alias: X dead after KV gemm, AO written by attn (later on stream)
  u16* Wot = Wqt;   // alias: Wqt dead after Q gemm, Wot transposed after it

  conv_bf16<<<2048, 256, 0, stream>>>(X, Xb, NROW * HID / 4);
  transpose_conv<<<dim3(64, 64), dim3(32, 8), 0, stream>>>(Wq, Wqt, HID, HID);
  transpose_conv<<<dim3(16, 64), dim3(32, 8), 0, stream>>>(Wk, Wkt, HID, KVH);
  transpose_conv<<<dim3(16, 64), dim3(32, 8), 0, stream>>>(Wv, Wvt, HID, KVH);
  gemm_bt<1><<<dim3(16, 32), 256, 0, stream>>>(Xb, Wqt, Wqt, Qb, Qb, 16, HID, HID);
  gemm_bt<1><<<dim3(8, 32), 256, 0, stream>>>(Xb, Wkt, Wvt, Kb, Vb, 4, KVH, HID);
  transpose_conv<<<dim3(64, 64), dim3(32, 8), 0, stream>>>(Wo, Wot, HID, HID);
  attn_mfma<<<dim3(8, 32, 2), 256, 0, stream>>>(Qb, Kb, Vb, AOb);
  gemm_bt<0><<<dim3(16, 32), 256, 0, stream>>>(AOb, Wot, Wot, out, out, 16, HID, HID);
}